// Round 1
// baseline (697.535 us; speedup 1.0000x reference)
//
#include <hip/hip_runtime.h>

#define THREADS 256
#define F_HID 10
#define F_OUT 19

// out[e, k] = b2[k] + sum_j relu(b1[j] + src*W1[0,j] + dest*W1[1,j] + ea*W1[2,j] + u[batch[e]]*W1[3,j]) * W2[j,k]
__global__ __launch_bounds__(THREADS) void edge_mlp_kernel(
    const float* __restrict__ src,
    const float* __restrict__ dst,
    const float* __restrict__ ea,
    const float* __restrict__ u,      // [B,1], B=4096 -> 16 KB, L1-resident
    const int*   __restrict__ batch,  // [E] int32
    const float* __restrict__ W1,     // [4,10] row-major
    const float* __restrict__ b1,     // [10]
    const float* __restrict__ W2,     // [10,19] row-major
    const float* __restrict__ b2,     // [19]
    float* __restrict__ out,          // [E,19]
    int n_edges)
{
    // Staging buffer: one block's worth of output, laid out exactly as the
    // global region it maps to -> flat float4 copy at the end is coalesced.
    __shared__ float lds[THREADS * F_OUT]; // 19456 B

    const int tid = threadIdx.x;
    const int e   = blockIdx.x * THREADS + tid;

    float o[F_OUT];
    if (e < n_edges) {
        const float x0 = src[e];
        const float x1 = dst[e];
        const float x2 = ea[e];
        const float x3 = u[batch[e]];

        #pragma unroll
        for (int k = 0; k < F_OUT; ++k) o[k] = b2[k];

        // j-loop: ~24 live uniform scalars per iteration (W1 col j, b1[j], W2 row j).
        // All weight reads are wave-uniform -> compiler emits s_load (broadcast).
        #pragma unroll
        for (int j = 0; j < F_HID; ++j) {
            float a = b1[j];
            a = fmaf(x0, W1[0 * F_HID + j], a);
            a = fmaf(x1, W1[1 * F_HID + j], a);
            a = fmaf(x2, W1[2 * F_HID + j], a);
            a = fmaf(x3, W1[3 * F_HID + j], a);
            a = fmaxf(a, 0.0f);  // ReLU
            #pragma unroll
            for (int k = 0; k < F_OUT; ++k)
                o[k] = fmaf(a, W2[j * F_OUT + k], o[k]);
        }
    } else {
        #pragma unroll
        for (int k = 0; k < F_OUT; ++k) o[k] = 0.0f;
    }

    // Stage to LDS. Inter-lane stride = 19 floats (odd) -> (19*i + k) % 32
    // hits each bank exactly twice per wave64 = 2-way = free (m136).
    #pragma unroll
    for (int k = 0; k < F_OUT; ++k) lds[tid * F_OUT + k] = o[k];
    __syncthreads();

    // Coalesced block-flat copy to global: 4864 floats = 1216 float4.
    const int block_start = blockIdx.x * THREADS;
    const int base = block_start * F_OUT;           // max 152M < 2^31, fits int
    int valid = n_edges - block_start;
    if (valid >= THREADS) {
        // full block: vector copy (base*4 bytes % 16 == 0 since 19456 % 16 == 0)
        float4* __restrict__ outv = (float4*)(out + base);
        const float4* __restrict__ ldsv = (const float4*)lds;
        #pragma unroll
        for (int idx = tid; idx < (THREADS * F_OUT) / 4; idx += THREADS)
            outv[idx] = ldsv[idx];
    } else {
        // tail block (not hit for E=8M, kept for generality): scalar copy
        const int nflt = valid * F_OUT;
        for (int idx = tid; idx < nflt; idx += THREADS)
            out[base + idx] = lds[idx];
    }
}

extern "C" void kernel_launch(void* const* d_in, const int* in_sizes, int n_in,
                              void* d_out, int out_size, void* d_ws, size_t ws_size,
                              hipStream_t stream) {
    const float* src   = (const float*)d_in[0];
    const float* dst   = (const float*)d_in[1];
    const float* ea    = (const float*)d_in[2];
    const float* u     = (const float*)d_in[3];
    const int*   batch = (const int*)  d_in[4];
    const float* W1    = (const float*)d_in[5];
    const float* b1    = (const float*)d_in[6];
    const float* W2    = (const float*)d_in[7];
    const float* b2    = (const float*)d_in[8];
    float* out = (float*)d_out;

    const int n = in_sizes[0];  // E (src is [E,1])
    const int blocks = (n + THREADS - 1) / THREADS;  // 31250 for E=8M
    edge_mlp_kernel<<<blocks, THREADS, 0, stream>>>(
        src, dst, ea, u, batch, W1, b1, W2, b2, out, n);
}